// Round 10
// baseline (185.152 us; speedup 1.0000x reference)
//
#include <hip/hip_runtime.h>

typedef short short8 __attribute__((ext_vector_type(8)));
typedef unsigned short ushort8 __attribute__((ext_vector_type(8)));
typedef float f32x4 __attribute__((ext_vector_type(4)));

__device__ __forceinline__ unsigned short f32_to_bf16(float f) {
  unsigned u = __float_as_uint(f);
  unsigned r = 0x7fffu + ((u >> 16) & 1u);
  return (unsigned short)((u + r) >> 16);
}

// ---------------- f32 -> bf16 convert (vectorized, 8 elems/thread) ----------
__global__ void cvt_f32_bf16(const float* __restrict__ s,
                             unsigned short* __restrict__ d, int n8) {
  int i = blockIdx.x * blockDim.x + threadIdx.x;
  if (i >= n8) return;
  const float4* sp = (const float4*)s;
  float4 a = sp[2 * i], b = sp[2 * i + 1];
  ushort8 o;
  o[0] = f32_to_bf16(a.x); o[1] = f32_to_bf16(a.y);
  o[2] = f32_to_bf16(a.z); o[3] = f32_to_bf16(a.w);
  o[4] = f32_to_bf16(b.x); o[5] = f32_to_bf16(b.y);
  o[6] = f32_to_bf16(b.z); o[7] = f32_to_bf16(b.w);
  ((ushort8*)d)[i] = o;
}

// ---------------- async global->LDS (16B/lane, wave-uniform LDS base) -------
__device__ __forceinline__ void gload_lds16(const void* g, void* l) {
  auto* gp = (const __attribute__((address_space(1))) uint32_t*)((uintptr_t)g);
  auto* lp = (__attribute__((address_space(3))) uint32_t*)(uint32_t)(uintptr_t)l;
  __builtin_amdgcn_global_load_lds(gp, lp, 16, 0, 0);
}

// ---------------- twiddle tables: e^{2*pi*i*k/16} ----------------------------
constexpr float C16T[16] = {
    1.f,  0.9238795325112867f,  0.7071067811865476f,  0.3826834323650898f,
    0.f, -0.3826834323650898f, -0.7071067811865476f, -0.9238795325112867f,
   -1.f, -0.9238795325112867f, -0.7071067811865476f, -0.3826834323650898f,
    0.f,  0.3826834323650898f,  0.7071067811865476f,  0.9238795325112867f};
constexpr float S16T[16] = {
    0.f,  0.3826834323650898f,  0.7071067811865476f,  0.9238795325112867f,
    1.f,  0.9238795325112867f,  0.7071067811865476f,  0.3826834323650898f,
    0.f, -0.3826834323650898f, -0.7071067811865476f, -0.9238795325112867f,
   -1.f, -0.9238795325112867f, -0.7071067811865476f, -0.3826834323650898f};

// ---------------- build circulant spectral operator --------------------------
// ifft2(fft2(h)*F) == circular-conv(h, G), G = ifft2(F) (16x16 complex).
// Gpp [512][256] bf16: for out-pixel p, row (p>>5)*64+(p&31) = re,
// row +32 = im; Gpp[row][q] = G[(p1-q1)&15][(p2-q2)&15].
__global__ __launch_bounds__(256) void build_gpp(
    const float* __restrict__ fre, const float* __restrict__ fim,
    unsigned short* __restrict__ Gpp) {
  __shared__ float Gr[256], Gi[256];
  const int t = threadIdx.x;
  const int d1 = t >> 4, d2 = t & 15;
  float sr = 0.f, si = 0.f;
#pragma unroll
  for (int v1 = 0; v1 < 16; ++v1) {
    const int k1 = (v1 * d1) & 15;
#pragma unroll
    for (int v2 = 0; v2 < 16; ++v2) {
      const int k = (k1 + v2 * d2) & 15;
      const float c = C16T[k], s = S16T[k];
      const float a = fre[v1 * 16 + v2], b = fim[v1 * 16 + v2];
      sr += a * c - b * s;
      si += a * s + b * c;
    }
  }
  Gr[t] = sr * (1.f / 256.f);
  Gi[t] = si * (1.f / 256.f);
  __syncthreads();
  const int p = blockIdx.x;
  const int p1 = p >> 4, p2 = p & 15;
  const size_t rre = (size_t)(p >> 5) * 64 + (p & 31);
  const int q1 = t >> 4, q2 = t & 15;
  const int idx = (((p1 - q1) & 15) << 4) | ((p2 - q2) & 15);
  Gpp[rre * 256 + t] = f32_to_bf16(Gr[idx]);
  Gpp[(rre + 32) * 256 + t] = f32_to_bf16(Gi[idx]);
}

// ---------------- BK=32 high-occupancy MFMA GEMM -----------------------------
// C = A[M,K] * B[*,K]^T. 128x128 tile, BK=32, 4 waves, 2-phase prefetch,
// dbuf LDS = 32 KB total -> 5 blocks/CU = 20 waves/CU (was 2 blocks/8 waves:
// the R1-R9 latency bottleneck). Swizzle: 64B rows, 4x16B slots; slot s of
// row r stored at s^((r>>1)&3) via pre-swizzled global src (rule #21);
// read with same key -> <=2-way bank aliasing (free).
// MODE 0: f32 out + bias. MODE 1: bf16 out + bias.
// MODE 2: magnitude |re,im| bf16 out (interleaved B rows), no bias, ld=ldo.
template <int MODE>
__global__ __launch_bounds__(256, 5) void gemm32(
    const unsigned short* __restrict__ A, const unsigned short* __restrict__ B,
    const float* __restrict__ bias, void* __restrict__ out,
    int M, int K, int nbx, int ldo) {
  __shared__ __align__(16) unsigned short As[2][128 * 32];
  __shared__ __align__(16) unsigned short Bs[2][128 * 32];

  const int tid = threadIdx.x;
  const int lane = tid & 63;
  const int wid = tid >> 6;
  const int wr = wid >> 1, wc = wid & 1;

  // XCD-chunked swizzle (grid %8 == 0)
  const int nwg = gridDim.x;
  const int cpx = nwg >> 3;
  const int bid = blockIdx.x;
  const int lid = (bid & 7) * cpx + (bid >> 3);
  const int m0 = (lid / nbx) * 128, n0 = (lid % nbx) * 128;

  // staging: round l covers rows l*64 + (tid>>2), slot tid&3 (16B units).
  // pre-swizzled global slot: (tid&3) ^ ((row>>1)&3), row64 = tid>>2.
  const int srow = tid >> 2;
  const int sgo = (((tid & 3) ^ ((tid >> 3) & 3)) << 3);  // k-elem offset
  char* AsC = (char*)&As[0][0];
  char* BsC = (char*)&Bs[0][0];

  auto STAGE = [&](int buf, int kt) {
    const int k0 = kt * 32 + sgo;
#pragma unroll
    for (int l = 0; l < 2; ++l) {
      gload_lds16(A + (size_t)(m0 + l * 64 + srow) * K + k0,
                  AsC + buf * 8192 + l * 4096 + (wid << 10));
      gload_lds16(B + (size_t)(n0 + l * 64 + srow) * K + k0,
                  BsC + buf * 8192 + l * 4096 + (wid << 10));
    }
  };

  // read: row r, want k-slot (lane>>4) -> lds slot (lane>>4)^((r>>1)&3);
  // (r>>1)&3 == (lane>>1)&3 for all fragment rows (r = base16 + (lane&15)).
  const int rsel = lane & 15;
  const int kslot = ((lane >> 4) ^ ((lane >> 1) & 3)) << 4;  // byte offset

  f32x4 acc[4][4] = {};

  auto COMPUTE = [&](int buf) {
    const char* Ab = AsC + buf * 8192;
    const char* Bb = BsC + buf * 8192;
    short8 af[4], bf[4];
#pragma unroll
    for (int m = 0; m < 4; ++m)
      af[m] = *(const short8*)(Ab + (wr * 64 + m * 16 + rsel) * 64 + kslot);
#pragma unroll
    for (int n = 0; n < 4; ++n)
      bf[n] = *(const short8*)(Bb + (wc * 64 + n * 16 + rsel) * 64 + kslot);
#pragma unroll
    for (int m = 0; m < 4; ++m)
#pragma unroll
      for (int n = 0; n < 4; ++n)
        acc[m][n] = __builtin_amdgcn_mfma_f32_16x16x32_bf16(
            af[m], bf[n], acc[m][n], 0, 0, 0);
  };

  const int nk = K >> 5;
  STAGE(0, 0);
  __syncthreads();
  int cur = 0;
  for (int t = 1; t < nk; ++t) {
    STAGE(cur ^ 1, t);
    COMPUTE(cur);
    __syncthreads();
    cur ^= 1;
  }
  COMPUTE(cur);

  // C/D layout: col = lane&15, row = (lane>>4)*4 + j
  const int fr = lane & 15, fq = lane >> 4;
  if (MODE == 2) {
    // B rows [n0+wc*64, +64) = {re,im} of 32 output pixels
    const int cbase = (n0 + wc * 64) >> 1;
    unsigned short* o = (unsigned short*)out;
#pragma unroll
    for (int n = 0; n < 2; ++n) {
      const int gcol = cbase + n * 16 + fr;
#pragma unroll
      for (int m = 0; m < 4; ++m) {
        const int grow = m0 + wr * 64 + m * 16 + fq * 4;
#pragma unroll
        for (int j = 0; j < 4; ++j) {
          const float re = acc[m][n][j];
          const float im = acc[m][n + 2][j];
          o[(size_t)(grow + j) * ldo + gcol] =
              f32_to_bf16(sqrtf(re * re + im * im));
        }
      }
    }
  } else {
#pragma unroll
    for (int n = 0; n < 4; ++n) {
      const int gcol = n0 + wc * 64 + n * 16 + fr;
      const float bv = bias[gcol];
#pragma unroll
      for (int m = 0; m < 4; ++m) {
        const int grow = m0 + wr * 64 + m * 16 + fq * 4;
#pragma unroll
        for (int j = 0; j < 4; ++j) {
          const float v = acc[m][n][j] + bv;
          if (MODE == 1)
            ((unsigned short*)out)[(size_t)(grow + j) * ldo + gcol] =
                f32_to_bf16(v);
          else
            ((float*)out)[(size_t)(grow + j) * ldo + gcol] = v;
        }
      }
    }
  }
}

// ---------------- launcher ---------------------------------------------------
extern "C" void kernel_launch(void* const* d_in, const int* in_sizes, int n_in,
                              void* d_out, int out_size, void* d_ws,
                              size_t ws_size, hipStream_t stream) {
  const float* x   = (const float*)d_in[0];
  const float* We  = (const float*)d_in[1];
  const float* be  = (const float*)d_in[2];
  const float* fre = (const float*)d_in[3];
  const float* fim = (const float*)d_in[4];
  const float* Wd  = (const float*)d_in[5];
  const float* bd  = (const float*)d_in[6];

  const int E = 768, C = 768;
  const int nX = in_sizes[0];                  // 19,267,584
  const int M  = nX / E;                       // 25088
  const int nW = E * C;                        // 589,824

  char* w = (char*)d_ws;
  unsigned short* xb  = (unsigned short*)w;                      // nX bf16 (reused as ab)
  unsigned short* Web = (unsigned short*)(w + (size_t)nX * 2);   // nW bf16
  unsigned short* Wdb = Web + nW;                                // nW bf16
  unsigned short* Gpp = Wdb + nW;                                // 512*256 bf16
  unsigned short* hb  = Gpp + 512 * 256;                         // nX bf16

  cvt_f32_bf16<<<(nX / 8 + 255) / 256, 256, 0, stream>>>(x, xb, nX / 8);
  cvt_f32_bf16<<<(nW / 8 + 255) / 256, 256, 0, stream>>>(We, Web, nW / 8);
  cvt_f32_bf16<<<(nW / 8 + 255) / 256, 256, 0, stream>>>(Wd, Wdb, nW / 8);

  // circulant spectral operator G = ifft2(filter), interleaved re/im rows
  build_gpp<<<256, 256, 0, stream>>>(fre, fim, Gpp);

  // h = x @ We^T + be  (bf16); grid 1176 = 196*6, m-major
  gemm32<1><<<6 * (M / 128), 256, 0, stream>>>(xb, Web, be, hb, M, E, 6, 768);

  // a = |h (.) G| : [75264,256] @ Gpp[512,256]^T -> ab (= xb); grid 2352
  const int M2 = M * 3;
  gemm32<2><<<4 * (M2 / 128), 256, 0, stream>>>(hb, Gpp, nullptr, xb, M2, 256,
                                                4, 256);

  // out = a @ Wd^T + bd  (f32); grid 1176
  gemm32<0><<<6 * (M / 128), 256, 0, stream>>>(xb, Wdb, bd, (float*)d_out, M,
                                               C, 6, 768);
}

// Round 11
// 153.954 us; speedup vs baseline: 1.2026x; 1.2026x over previous
//
#include <hip/hip_runtime.h>

typedef short short8 __attribute__((ext_vector_type(8)));
typedef unsigned short ushort8 __attribute__((ext_vector_type(8)));
typedef float f32x4 __attribute__((ext_vector_type(4)));

__device__ __forceinline__ unsigned short f32_to_bf16(float f) {
  unsigned u = __float_as_uint(f);
  unsigned r = 0x7fffu + ((u >> 16) & 1u);
  return (unsigned short)((u + r) >> 16);
}

// packed f32x2 -> bf16x2 (RNE), single VALU inst
__device__ __forceinline__ unsigned cvtpk_bf16(float lo, float hi) {
  unsigned r;
  asm volatile("v_cvt_pk_bf16_f32 %0, %1, %2" : "=v"(r) : "v"(lo), "v"(hi));
  return r;
}

// ---------------- f32 -> bf16 convert (weights only now) --------------------
__global__ void cvt_f32_bf16(const float* __restrict__ s,
                             unsigned short* __restrict__ d, int n8) {
  int i = blockIdx.x * blockDim.x + threadIdx.x;
  if (i >= n8) return;
  const float4* sp = (const float4*)s;
  float4 a = sp[2 * i], b = sp[2 * i + 1];
  ushort8 o;
  o[0] = f32_to_bf16(a.x); o[1] = f32_to_bf16(a.y);
  o[2] = f32_to_bf16(a.z); o[3] = f32_to_bf16(a.w);
  o[4] = f32_to_bf16(b.x); o[5] = f32_to_bf16(b.y);
  o[6] = f32_to_bf16(b.z); o[7] = f32_to_bf16(b.w);
  ((ushort8*)d)[i] = o;
}

// ---------------- async global->LDS (16B/lane, wave-uniform LDS base) -------
__device__ __forceinline__ void gload_lds16(const void* g, void* l) {
  auto* gp = (const __attribute__((address_space(1))) uint32_t*)((uintptr_t)g);
  auto* lp = (__attribute__((address_space(3))) uint32_t*)(uint32_t)(uintptr_t)l;
  __builtin_amdgcn_global_load_lds(gp, lp, 16, 0, 0);
}

// ---------------- twiddle tables: e^{2*pi*i*k/16} ----------------------------
constexpr float C16T[16] = {
    1.f,  0.9238795325112867f,  0.7071067811865476f,  0.3826834323650898f,
    0.f, -0.3826834323650898f, -0.7071067811865476f, -0.9238795325112867f,
   -1.f, -0.9238795325112867f, -0.7071067811865476f, -0.3826834323650898f,
    0.f,  0.3826834323650898f,  0.7071067811865476f,  0.9238795325112867f};
constexpr float S16T[16] = {
    0.f,  0.3826834323650898f,  0.7071067811865476f,  0.9238795325112867f,
    1.f,  0.9238795325112867f,  0.7071067811865476f,  0.3826834323650898f,
    0.f, -0.3826834323650898f, -0.7071067811865476f, -0.9238795325112867f,
   -1.f, -0.9238795325112867f, -0.7071067811865476f, -0.3826834323650898f};

// ---------------- build circulant spectral operator --------------------------
// ifft2(fft2(h)*F) == circular-conv(h, G), G = ifft2(F) (16x16 complex).
// Gpp [512][256] bf16: for out-pixel p, row (p>>5)*64+(p&31) = re,
// row +32 = im; Gpp[row][q] = G[(p1-q1)&15][(p2-q2)&15].
__global__ __launch_bounds__(256) void build_gpp(
    const float* __restrict__ fre, const float* __restrict__ fim,
    unsigned short* __restrict__ Gpp) {
  __shared__ float Gr[256], Gi[256];
  const int t = threadIdx.x;
  const int d1 = t >> 4, d2 = t & 15;
  float sr = 0.f, si = 0.f;
#pragma unroll
  for (int v1 = 0; v1 < 16; ++v1) {
    const int k1 = (v1 * d1) & 15;
#pragma unroll
    for (int v2 = 0; v2 < 16; ++v2) {
      const int k = (k1 + v2 * d2) & 15;
      const float c = C16T[k], s = S16T[k];
      const float a = fre[v1 * 16 + v2], b = fim[v1 * 16 + v2];
      sr += a * c - b * s;
      si += a * s + b * c;
    }
  }
  Gr[t] = sr * (1.f / 256.f);
  Gi[t] = si * (1.f / 256.f);
  __syncthreads();
  const int p = blockIdx.x;
  const int p1 = p >> 4, p2 = p & 15;
  const size_t rre = (size_t)(p >> 5) * 64 + (p & 31);
  const int q1 = t >> 4, q2 = t & 15;
  const int idx = (((p1 - q1) & 15) << 4) | ((p2 - q2) & 15);
  Gpp[rre * 256 + t] = f32_to_bf16(Gr[idx]);
  Gpp[(rre + 32) * 256 + t] = f32_to_bf16(Gi[idx]);
}

// ---------------- encode GEMM with fused f32->bf16 A staging ----------------
// h = X[M,K f32] @ B[768,K bf16]^T + be, bf16 out. 128x128 tile, BK=64,
// 4 waves, 2-phase prefetch, dbuf LDS, XOR-swizzle (write key row&7 = read
// key), XCD chunking, m-major. A staged via registers (T14 issue-early /
// write-late): 8x dwordx4 f32 loads issued before COMPUTE, cvt_pk after.
__global__ __launch_bounds__(256) void gemm_encx(
    const float* __restrict__ X, const unsigned short* __restrict__ B,
    const float* __restrict__ bias, unsigned short* __restrict__ out,
    int M, int K, int nbx) {
  __shared__ __align__(16) unsigned short As[2][128 * 64];
  __shared__ __align__(16) unsigned short Bs[2][128 * 64];

  const int tid = threadIdx.x;
  const int lane = tid & 63;
  const int wid = tid >> 6;
  const int wr = wid >> 1, wc = wid & 1;

  const int nwg = gridDim.x;
  const int cpx = nwg >> 3;
  const int bid = blockIdx.x;
  const int lid = (bid & 7) * cpx + (bid >> 3);
  const int m0 = (lid / nbx) * 128, n0 = (lid % nbx) * 128;

  // B staging (gload_lds, pre-swizzled source)
  const int lr8 = lane >> 3;
  const int swk = ((lane & 7) ^ lr8) * 8;
  auto STAGE_B = [&](int buf, int k0) {
#pragma unroll
    for (int c = 0; c < 4; ++c) {
      const int rowc = wid * 32 + c * 8;
      gload_lds16(B + (size_t)(n0 + rowc + lr8) * K + (k0 + swk),
                  &Bs[buf][rowc * 64]);
    }
  };

  // A reg staging: thread t handles rows arow+32l (l=0..3), k-slot aslot
  const int arow = tid >> 3;            // 0..31
  const int aslot = tid & 7;            // 8 f32 per slot
  const int awslot = aslot ^ (arow & 7);  // XOR swizzle write key
  float4 xa[4][2];
  auto ISSUE_A = [&](int kt) {
    const float* bp = X + (size_t)(m0 + arow) * K + kt * 64 + aslot * 8;
#pragma unroll
    for (int l = 0; l < 4; ++l) {
      xa[l][0] = *(const float4*)(bp + (size_t)(32 * l) * K);
      xa[l][1] = *(const float4*)(bp + (size_t)(32 * l) * K + 4);
    }
  };
  auto WRITE_A = [&](int buf) {
#pragma unroll
    for (int l = 0; l < 4; ++l) {
      uint4 pk;
      pk.x = cvtpk_bf16(xa[l][0].x, xa[l][0].y);
      pk.y = cvtpk_bf16(xa[l][0].z, xa[l][0].w);
      pk.z = cvtpk_bf16(xa[l][1].x, xa[l][1].y);
      pk.w = cvtpk_bf16(xa[l][1].z, xa[l][1].w);
      *(uint4*)((char*)&As[buf][0] + (arow + 32 * l) * 128 + awslot * 16) = pk;
    }
  };

  const int rsel = lane & 15;
  f32x4 acc[4][4] = {};
  auto COMPUTE = [&](int buf) {
#pragma unroll
    for (int ks = 0; ks < 2; ++ks) {
      const int kbyte = ks * 64 + (lane >> 4) * 16;
      short8 af[4], bf[4];
#pragma unroll
      for (int m = 0; m < 4; ++m) {
        const int row = wr * 64 + m * 16 + rsel;
        af[m] = *(const short8*)((const char*)&As[buf][0] +
                                 row * 128 + (kbyte ^ ((row & 7) << 4)));
      }
#pragma unroll
      for (int n = 0; n < 4; ++n) {
        const int row = wc * 64 + n * 16 + rsel;
        bf[n] = *(const short8*)((const char*)&Bs[buf][0] +
                                 row * 128 + (kbyte ^ ((row & 7) << 4)));
      }
#pragma unroll
      for (int m = 0; m < 4; ++m)
#pragma unroll
        for (int n = 0; n < 4; ++n)
          acc[m][n] = __builtin_amdgcn_mfma_f32_16x16x32_bf16(
              af[m], bf[n], acc[m][n], 0, 0, 0);
    }
  };

  const int nk = K >> 6;
  ISSUE_A(0);
  STAGE_B(0, 0);
  WRITE_A(0);          // compiler inserts exact vmcnt for xa deps
  __syncthreads();     // drains B gloads + A ds_writes
  int cur = 0;
  for (int t = 1; t < nk; ++t) {
    ISSUE_A(t);              // issue early: COMPUTE hides the latency
    STAGE_B(cur ^ 1, t * 64);
    COMPUTE(cur);
    WRITE_A(cur ^ 1);        // write late (prev barrier certified buf free)
    __syncthreads();
    cur ^= 1;
  }
  COMPUTE(cur);

  const int fr = lane & 15, fq = lane >> 4;
#pragma unroll
  for (int n = 0; n < 4; ++n) {
    const int gcol = n0 + wc * 64 + n * 16 + fr;
    const float bv = bias[gcol];
#pragma unroll
    for (int m = 0; m < 4; ++m) {
      const int grow = m0 + wr * 64 + m * 16 + fq * 4;
#pragma unroll
      for (int j = 0; j < 4; ++j)
        out[(size_t)(grow + j) * 768 + gcol] = f32_to_bf16(acc[m][n][j] + bv);
    }
  }
}

// ---------------- GEMM: C = A * B^T + bias (R9 proven body) -----------------
template <int OUT_BF16>
__global__ __launch_bounds__(256) void gemm_bt(
    const unsigned short* __restrict__ A, const unsigned short* __restrict__ B,
    const float* __restrict__ bias, void* __restrict__ out,
    int M, int N, int K, int nbx) {
  __shared__ __align__(16) unsigned short As[2][128 * 64];
  __shared__ __align__(16) unsigned short Bs[2][128 * 64];

  const int tid = threadIdx.x;
  const int lane = tid & 63;
  const int wid = tid >> 6;
  const int wr = wid >> 1, wc = wid & 1;

  const int nwg = gridDim.x;
  const int cpx = nwg >> 3;
  const int bid = blockIdx.x;
  const int lid = (bid & 7) * cpx + (bid >> 3);
  const int m0 = (lid / nbx) * 128, n0 = (lid % nbx) * 128;

  const int lr8 = lane >> 3;
  const int swk = ((lane & 7) ^ lr8) * 8;

  f32x4 acc[4][4] = {};

  auto STAGE = [&](int buf, int k0) {
#pragma unroll
    for (int c = 0; c < 4; ++c) {
      const int rowc = wid * 32 + c * 8;
      gload_lds16(A + (size_t)(m0 + rowc + lr8) * K + (k0 + swk),
                  &As[buf][rowc * 64]);
      gload_lds16(B + (size_t)(n0 + rowc + lr8) * K + (k0 + swk),
                  &Bs[buf][rowc * 64]);
    }
  };

  const int rsel = lane & 15;
  auto COMPUTE = [&](int buf) {
#pragma unroll
    for (int ks = 0; ks < 2; ++ks) {
      const int kbyte = ks * 64 + (lane >> 4) * 16;
      short8 af[4], bf[4];
#pragma unroll
      for (int m = 0; m < 4; ++m) {
        const int row = wr * 64 + m * 16 + rsel;
        af[m] = *(const short8*)((const char*)&As[buf][0] +
                                 row * 128 + (kbyte ^ ((row & 7) << 4)));
      }
#pragma unroll
      for (int n = 0; n < 4; ++n) {
        const int row = wc * 64 + n * 16 + rsel;
        bf[n] = *(const short8*)((const char*)&Bs[buf][0] +
                                 row * 128 + (kbyte ^ ((row & 7) << 4)));
      }
#pragma unroll
      for (int m = 0; m < 4; ++m)
#pragma unroll
        for (int n = 0; n < 4; ++n)
          acc[m][n] = __builtin_amdgcn_mfma_f32_16x16x32_bf16(
              af[m], bf[n], acc[m][n], 0, 0, 0);
    }
  };

  const int nk = K >> 6;
  STAGE(0, 0);
  __syncthreads();
  int cur = 0;
  for (int t = 1; t < nk; ++t) {
    STAGE(cur ^ 1, t * 64);
    COMPUTE(cur);
    __syncthreads();
    cur ^= 1;
  }
  COMPUTE(cur);

  const int fr = lane & 15, fq = lane >> 4;
#pragma unroll
  for (int n = 0; n < 4; ++n) {
    const int gcol = n0 + wc * 64 + n * 16 + fr;
    const float bv = bias[gcol];
#pragma unroll
    for (int m = 0; m < 4; ++m) {
      const int grow = m0 + wr * 64 + m * 16 + fq * 4;
#pragma unroll
      for (int j = 0; j < 4; ++j) {
        const float v = acc[m][n][j] + bv;
        if (OUT_BF16)
          ((unsigned short*)out)[(size_t)(grow + j) * N + gcol] = f32_to_bf16(v);
        else
          ((float*)out)[(size_t)(grow + j) * N + gcol] = v;
      }
    }
  }
}

// ---------------- spectral GEMM: a = |h2 @ Gpp^T|, bf16 out (R9 body) -------
__global__ __launch_bounds__(256) void gemm_spec(
    const unsigned short* __restrict__ A, const unsigned short* __restrict__ B,
    unsigned short* __restrict__ out, int M2, int nbx) {
  __shared__ __align__(16) unsigned short As[2][128 * 64];
  __shared__ __align__(16) unsigned short Bs[2][128 * 64];

  const int K = 256;
  const int tid = threadIdx.x;
  const int lane = tid & 63;
  const int wid = tid >> 6;
  const int wr = wid >> 1, wc = wid & 1;

  const int nwg = gridDim.x;
  const int cpx = nwg >> 3;
  const int bid = blockIdx.x;
  const int lid = (bid & 7) * cpx + (bid >> 3);
  const int m0 = (lid / nbx) * 128, n0 = (lid % nbx) * 128;

  const int lr8 = lane >> 3;
  const int swk = ((lane & 7) ^ lr8) * 8;

  f32x4 acc[4][4] = {};

  auto STAGE = [&](int buf, int k0) {
#pragma unroll
    for (int c = 0; c < 4; ++c) {
      const int rowc = wid * 32 + c * 8;
      gload_lds16(A + (size_t)(m0 + rowc + lr8) * K + (k0 + swk),
                  &As[buf][rowc * 64]);
      gload_lds16(B + (size_t)(n0 + rowc + lr8) * K + (k0 + swk),
                  &Bs[buf][rowc * 64]);
    }
  };

  const int rsel = lane & 15;
  auto COMPUTE = [&](int buf) {
#pragma unroll
    for (int ks = 0; ks < 2; ++ks) {
      const int kbyte = ks * 64 + (lane >> 4) * 16;
      short8 af[4], bf[4];
#pragma unroll
      for (int m = 0; m < 4; ++m) {
        const int row = wr * 64 + m * 16 + rsel;
        af[m] = *(const short8*)((const char*)&As[buf][0] +
                                 row * 128 + (kbyte ^ ((row & 7) << 4)));
      }
#pragma unroll
      for (int n = 0; n < 4; ++n) {
        const int row = wc * 64 + n * 16 + rsel;
        bf[n] = *(const short8*)((const char*)&Bs[buf][0] +
                                 row * 128 + (kbyte ^ ((row & 7) << 4)));
      }
#pragma unroll
      for (int m = 0; m < 4; ++m)
#pragma unroll
        for (int n = 0; n < 4; ++n)
          acc[m][n] = __builtin_amdgcn_mfma_f32_16x16x32_bf16(
              af[m], bf[n], acc[m][n], 0, 0, 0);
    }
  };

  const int nk = K >> 6;  // 4
  STAGE(0, 0);
  __syncthreads();
  int cur = 0;
  for (int t = 1; t < nk; ++t) {
    STAGE(cur ^ 1, t * 64);
    COMPUTE(cur);
    __syncthreads();
    cur ^= 1;
  }
  COMPUTE(cur);

  const int fr = lane & 15, fq = lane >> 4;
  const int cbase = (n0 + wc * 64) >> 1;
#pragma unroll
  for (int n = 0; n < 2; ++n) {
    const int gcol = cbase + n * 16 + fr;
#pragma unroll
    for (int m = 0; m < 4; ++m) {
      const int grow = m0 + wr * 64 + m * 16 + fq * 4;
#pragma unroll
      for (int j = 0; j < 4; ++j) {
        const float re = acc[m][n][j];
        const float im = acc[m][n + 2][j];
        out[(size_t)(grow + j) * 256 + gcol] =
            f32_to_bf16(sqrtf(re * re + im * im));
      }
    }
  }
}

// ---------------- launcher ---------------------------------------------------
extern "C" void kernel_launch(void* const* d_in, const int* in_sizes, int n_in,
                              void* d_out, int out_size, void* d_ws,
                              size_t ws_size, hipStream_t stream) {
  const float* x   = (const float*)d_in[0];
  const float* We  = (const float*)d_in[1];
  const float* be  = (const float*)d_in[2];
  const float* fre = (const float*)d_in[3];
  const float* fim = (const float*)d_in[4];
  const float* Wd  = (const float*)d_in[5];
  const float* bd  = (const float*)d_in[6];

  const int E = 768, C = 768;
  const int nX = in_sizes[0];                  // 19,267,584
  const int M  = nX / E;                       // 25088
  const int nW = E * C;                        // 589,824

  char* w = (char*)d_ws;
  unsigned short* Web = (unsigned short*)w;                      // nW bf16
  unsigned short* Wdb = Web + nW;                                // nW bf16
  unsigned short* Gpp = Wdb + nW;                                // 512*256 bf16
  unsigned short* hb  = Gpp + 512 * 256;                         // nX bf16
  unsigned short* ab  = hb + nX;                                 // nX bf16

  cvt_f32_bf16<<<(nW / 8 + 255) / 256, 256, 0, stream>>>(We, Web, nW / 8);
  cvt_f32_bf16<<<(nW / 8 + 255) / 256, 256, 0, stream>>>(Wd, Wdb, nW / 8);

  // circulant spectral operator G = ifft2(filter), interleaved re/im rows
  build_gpp<<<256, 256, 0, stream>>>(fre, fim, Gpp);

  // h = x @ We^T + be  (bf16, A read as f32 + converted in-kernel); grid 1176
  gemm_encx<<<6 * (M / 128), 256, 0, stream>>>(x, Web, be, hb, M, E, 6);

  // a = |h (.) G| : [75264,256] @ Gpp[512,256]^T -> ab; grid 2352
  const int M2 = M * 3;
  gemm_spec<<<4 * (M2 / 128), 256, 0, stream>>>(hb, Gpp, ab, M2, 4);

  // out = a @ Wd^T + bd  (f32); grid 1176
  gemm_bt<0><<<6 * (M / 128), 256, 0, stream>>>(ab, Wdb, bd, (float*)d_out, M,
                                                E, C, 6);
}

// Round 12
// 153.359 us; speedup vs baseline: 1.2073x; 1.0039x over previous
//
#include <hip/hip_runtime.h>

typedef short short8 __attribute__((ext_vector_type(8)));
typedef unsigned short ushort8 __attribute__((ext_vector_type(8)));
typedef float f32x4 __attribute__((ext_vector_type(4)));

__device__ __forceinline__ unsigned short f32_to_bf16(float f) {
  unsigned u = __float_as_uint(f);
  unsigned r = 0x7fffu + ((u >> 16) & 1u);
  return (unsigned short)((u + r) >> 16);
}

// ---------------- f32 -> bf16 convert (vectorized, 8 elems/thread) ----------
__global__ void cvt_f32_bf16(const float* __restrict__ s,
                             unsigned short* __restrict__ d, int n8) {
  int i = blockIdx.x * blockDim.x + threadIdx.x;
  if (i >= n8) return;
  const float4* sp = (const float4*)s;
  float4 a = sp[2 * i], b = sp[2 * i + 1];
  ushort8 o;
  o[0] = f32_to_bf16(a.x); o[1] = f32_to_bf16(a.y);
  o[2] = f32_to_bf16(a.z); o[3] = f32_to_bf16(a.w);
  o[4] = f32_to_bf16(b.x); o[5] = f32_to_bf16(b.y);
  o[6] = f32_to_bf16(b.z); o[7] = f32_to_bf16(b.w);
  ((ushort8*)d)[i] = o;
}

// ---------------- async global->LDS (16B/lane, wave-uniform LDS base) -------
__device__ __forceinline__ void gload_lds16(const void* g, void* l) {
  auto* gp = (const __attribute__((address_space(1))) uint32_t*)((uintptr_t)g);
  auto* lp = (__attribute__((address_space(3))) uint32_t*)(uint32_t)(uintptr_t)l;
  __builtin_amdgcn_global_load_lds(gp, lp, 16, 0, 0);
}

// counted-vmcnt pipelined K-loop sync helpers (ledger in header comment below)
#define WAIT8()                                        \
  do {                                                 \
    asm volatile("s_waitcnt vmcnt(8)" ::: "memory");   \
  } while (0)
#define WAIT0()                                        \
  do {                                                 \
    asm volatile("s_waitcnt vmcnt(0)" ::: "memory");   \
  } while (0)
#define BAR()                                          \
  do {                                                 \
    __builtin_amdgcn_s_barrier();                      \
    __builtin_amdgcn_sched_barrier(0);                 \
  } while (0)

// ---------------- twiddle tables: e^{2*pi*i*k/16} ----------------------------
constexpr float C16T[16] = {
    1.f,  0.9238795325112867f,  0.7071067811865476f,  0.3826834323650898f,
    0.f, -0.3826834323650898f, -0.7071067811865476f, -0.9238795325112867f,
   -1.f, -0.9238795325112867f, -0.7071067811865476f, -0.3826834323650898f,
    0.f,  0.3826834323650898f,  0.7071067811865476f,  0.9238795325112867f};
constexpr float S16T[16] = {
    0.f,  0.3826834323650898f,  0.7071067811865476f,  0.9238795325112867f,
    1.f,  0.9238795325112867f,  0.7071067811865476f,  0.3826834323650898f,
    0.f, -0.3826834323650898f, -0.7071067811865476f, -0.9238795325112867f,
   -1.f, -0.9238795325112867f, -0.7071067811865476f, -0.3826834323650898f};

// ---------------- build circulant spectral operator --------------------------
// ifft2(fft2(h)*F) == circular-conv(h, G), G = ifft2(F) (16x16 complex).
// Gpp [512][256] bf16: for out-pixel p, row (p>>5)*64+(p&31) = re,
// row +32 = im; Gpp[row][q] = G[(p1-q1)&15][(p2-q2)&15].
__global__ __launch_bounds__(256) void build_gpp(
    const float* __restrict__ fre, const float* __restrict__ fim,
    unsigned short* __restrict__ Gpp) {
  __shared__ float Gr[256], Gi[256];
  const int t = threadIdx.x;
  const int d1 = t >> 4, d2 = t & 15;
  float sr = 0.f, si = 0.f;
#pragma unroll
  for (int v1 = 0; v1 < 16; ++v1) {
    const int k1 = (v1 * d1) & 15;
#pragma unroll
    for (int v2 = 0; v2 < 16; ++v2) {
      const int k = (k1 + v2 * d2) & 15;
      const float c = C16T[k], s = S16T[k];
      const float a = fre[v1 * 16 + v2], b = fim[v1 * 16 + v2];
      sr += a * c - b * s;
      si += a * s + b * c;
    }
  }
  Gr[t] = sr * (1.f / 256.f);
  Gi[t] = si * (1.f / 256.f);
  __syncthreads();
  const int p = blockIdx.x;
  const int p1 = p >> 4, p2 = p & 15;
  const size_t rre = (size_t)(p >> 5) * 64 + (p & 31);
  const int q1 = t >> 4, q2 = t & 15;
  const int idx = (((p1 - q1) & 15) << 4) | ((p2 - q2) & 15);
  Gpp[rre * 256 + t] = f32_to_bf16(Gr[idx]);
  Gpp[(rre + 32) * 256 + t] = f32_to_bf16(Gi[idx]);
}

// ---------------- counted-vmcnt 128x128 MFMA GEMM ----------------------------
// C = A[M,K] * B[*,K]^T. 128x128 tile, BK=64, 4 waves, dbuf LDS, XOR-swizzle,
// XCD chunking, m-major. K-loop sync ledger (8 gload_lds/thread per tile):
//   prologue: STAGE(buf0,t0), STAGE(buf1,t1)          // <=16 in flight
//   iter t:   vmcnt(8) [last: vmcnt(0)]  -> tile t's loads landed, t+1 flying
//             BAR1 -> cross-wave: tile t fully resident in LDS
//             COMPUTE(t&1)
//             BAR2 -> all waves done reading buf t&1 (WAR safe)
//             if (t+2<nk) STAGE(t&1, t+2)             // issued 2 periods early
// No vmcnt(0) mid-loop: next tile's loads stay in flight across barriers (T4).
// MODE 0: f32 out + bias. MODE 1: bf16 out + bias.
// MODE 2: magnitude |re,im| (interleaved B rows), bf16 out, no bias.
template <int MODE>
__global__ __launch_bounds__(256) void gemm_cv(
    const unsigned short* __restrict__ A, const unsigned short* __restrict__ B,
    const float* __restrict__ bias, void* __restrict__ out,
    int M, int K, int nbx, int ldo) {
  __shared__ __align__(16) unsigned short As[2][128 * 64];
  __shared__ __align__(16) unsigned short Bs[2][128 * 64];

  const int tid = threadIdx.x;
  const int lane = tid & 63;
  const int wid = tid >> 6;
  const int wr = wid >> 1, wc = wid & 1;

  const int nwg = gridDim.x;
  const int cpx = nwg >> 3;
  const int bid = blockIdx.x;
  const int lid = (bid & 7) * cpx + (bid >> 3);
  const int m0 = (lid / nbx) * 128, n0 = (lid % nbx) * 128;

  const int lr8 = lane >> 3;
  const int swk = ((lane & 7) ^ lr8) * 8;

  f32x4 acc[4][4] = {};

  auto STAGE = [&](int buf, int kt) {
    const int k0 = kt * 64 + swk;
#pragma unroll
    for (int c = 0; c < 4; ++c) {
      const int rowc = wid * 32 + c * 8;
      gload_lds16(A + (size_t)(m0 + rowc + lr8) * K + k0, &As[buf][rowc * 64]);
      gload_lds16(B + (size_t)(n0 + rowc + lr8) * K + k0, &Bs[buf][rowc * 64]);
    }
  };

  const int rsel = lane & 15;
  auto COMPUTE = [&](int buf) {
#pragma unroll
    for (int ks = 0; ks < 2; ++ks) {
      const int kbyte = ks * 64 + (lane >> 4) * 16;
      short8 af[4], bf[4];
#pragma unroll
      for (int m = 0; m < 4; ++m) {
        const int row = wr * 64 + m * 16 + rsel;
        af[m] = *(const short8*)((const char*)&As[buf][0] +
                                 row * 128 + (kbyte ^ ((row & 7) << 4)));
      }
#pragma unroll
      for (int n = 0; n < 4; ++n) {
        const int row = wc * 64 + n * 16 + rsel;
        bf[n] = *(const short8*)((const char*)&Bs[buf][0] +
                                 row * 128 + (kbyte ^ ((row & 7) << 4)));
      }
#pragma unroll
      for (int m = 0; m < 4; ++m)
#pragma unroll
        for (int n = 0; n < 4; ++n)
          acc[m][n] = __builtin_amdgcn_mfma_f32_16x16x32_bf16(
              af[m], bf[n], acc[m][n], 0, 0, 0);
    }
  };

  const int nk = K >> 6;
  STAGE(0, 0);
  STAGE(1, 1);
  for (int t = 0; t < nk; ++t) {
    if (t + 1 < nk) WAIT8();   // tile t landed; tile t+1 stays in flight
    else            WAIT0();   // final tile: nothing newer
    BAR();                     // publish tile t to all waves
    COMPUTE(t & 1);
    __builtin_amdgcn_s_barrier();  // WAR: everyone done reading buf t&1
    if (t + 2 < nk) STAGE(t & 1, t + 2);
  }

  // C/D layout: col = lane&15, row = (lane>>4)*4 + j
  const int fr = lane & 15, fq = lane >> 4;
  if (MODE == 2) {
    const int cbase = (n0 + wc * 64) >> 1;  // 64 interleaved B-rows -> 32 cols
    unsigned short* o = (unsigned short*)out;
#pragma unroll
    for (int n = 0; n < 2; ++n) {
      const int gcol = cbase + n * 16 + fr;
#pragma unroll
      for (int m = 0; m < 4; ++m) {
        const int grow = m0 + wr * 64 + m * 16 + fq * 4;
#pragma unroll
        for (int j = 0; j < 4; ++j) {
          const float re = acc[m][n][j];
          const float im = acc[m][n + 2][j];
          o[(size_t)(grow + j) * ldo + gcol] =
              f32_to_bf16(sqrtf(re * re + im * im));
        }
      }
    }
  } else {
#pragma unroll
    for (int n = 0; n < 4; ++n) {
      const int gcol = n0 + wc * 64 + n * 16 + fr;
      const float bv = bias[gcol];
#pragma unroll
      for (int m = 0; m < 4; ++m) {
        const int grow = m0 + wr * 64 + m * 16 + fq * 4;
#pragma unroll
        for (int j = 0; j < 4; ++j) {
          const float v = acc[m][n][j] + bv;
          if (MODE == 1)
            ((unsigned short*)out)[(size_t)(grow + j) * ldo + gcol] =
                f32_to_bf16(v);
          else
            ((float*)out)[(size_t)(grow + j) * ldo + gcol] = v;
        }
      }
    }
  }
}

// ---------------- launcher ---------------------------------------------------
extern "C" void kernel_launch(void* const* d_in, const int* in_sizes, int n_in,
                              void* d_out, int out_size, void* d_ws,
                              size_t ws_size, hipStream_t stream) {
  const float* x   = (const float*)d_in[0];
  const float* We  = (const float*)d_in[1];
  const float* be  = (const float*)d_in[2];
  const float* fre = (const float*)d_in[3];
  const float* fim = (const float*)d_in[4];
  const float* Wd  = (const float*)d_in[5];
  const float* bd  = (const float*)d_in[6];

  const int E = 768, C = 768;
  const int nX = in_sizes[0];                  // 19,267,584
  const int M  = nX / E;                       // 25088
  const int nW = E * C;                        // 589,824

  char* w = (char*)d_ws;
  unsigned short* xb  = (unsigned short*)w;                      // nX bf16 (reused as ab)
  unsigned short* Web = (unsigned short*)(w + (size_t)nX * 2);   // nW bf16
  unsigned short* Wdb = Web + nW;                                // nW bf16
  unsigned short* Gpp = Wdb + nW;                                // 512*256 bf16
  unsigned short* hb  = Gpp + 512 * 256;                         // nX bf16

  cvt_f32_bf16<<<(nX / 8 + 255) / 256, 256, 0, stream>>>(x, xb, nX / 8);
  cvt_f32_bf16<<<(nW / 8 + 255) / 256, 256, 0, stream>>>(We, Web, nW / 8);
  cvt_f32_bf16<<<(nW / 8 + 255) / 256, 256, 0, stream>>>(Wd, Wdb, nW / 8);

  // circulant spectral operator G = ifft2(filter), interleaved re/im rows
  build_gpp<<<256, 256, 0, stream>>>(fre, fim, Gpp);

  // h = x @ We^T + be  (bf16); grid 1176 = 196*6, m-major
  gemm_cv<1><<<6 * (M / 128), 256, 0, stream>>>(xb, Web, be, hb, M, E, 6, 768);

  // a = |h (.) G| : [75264,256] @ Gpp[512,256]^T -> ab (= xb); grid 2352
  const int M2 = M * 3;
  gemm_cv<2><<<4 * (M2 / 128), 256, 0, stream>>>(hb, Gpp, nullptr, xb, M2, 256,
                                                 4, 256);

  // out = a @ Wd^T + bd  (f32); grid 1176
  gemm_cv<0><<<6 * (M / 128), 256, 0, stream>>>(xb, Wdb, bd, (float*)d_out, M,
                                                C, 6, 768);
}